// Round 1
// baseline (1177.645 us; speedup 1.0000x reference)
//
#include <hip/hip_runtime.h>
#include <cstdint>
#include <cstddef>

typedef unsigned short u16;
typedef __attribute__((ext_vector_type(8))) short bf16x8;
typedef __attribute__((ext_vector_type(4))) float f32x4;

__device__ __forceinline__ u16 f2bf(float f) {
    unsigned u = __float_as_uint(f);
    u += 0x7FFF + ((u >> 16) & 1);   // RNE
    return (u16)(u >> 16);
}
__device__ __forceinline__ float bf2f(u16 b) {
    return __uint_as_float(((unsigned)b) << 16);
}

// ---------------- fp32 -> bf16 conversion (4 elems/thread) ----------------
__global__ __launch_bounds__(256) void cvt_bf16(const float4* __restrict__ in,
                                                u16* __restrict__ out, int n4) {
    int i = blockIdx.x * 256 + threadIdx.x;
    if (i >= n4) return;
    float4 v = in[i];
    ushort4 o;
    o.x = f2bf(v.x); o.y = f2bf(v.y); o.z = f2bf(v.z); o.w = f2bf(v.w);
    ((ushort4*)out)[i] = o;
}

// ---------------- bf16 GEMM: C[M,N] = A[M,K] * Bt[N,K]^T ----------------
// 128x128 tile, BK=32, 4 waves (2x2), each wave 4x4 of 16x16x32 MFMA.
constexpr int BM = 128, BN = 128, BK = 32;

__device__ __forceinline__ void gl_lds16(const u16* g, u16* l) {
    __builtin_amdgcn_global_load_lds(
        (const __attribute__((address_space(1))) void*)g,
        (__attribute__((address_space(3))) void*)l, 16, 0, 0);
}

template <bool IS_QKV>
__global__ __launch_bounds__(256)
void gemm_bt(const u16* __restrict__ A, const u16* __restrict__ Bt,
             const float* __restrict__ bias, void* __restrict__ Cout,
             int M, int N, int K)
{
    __shared__ u16 As[BM * BK];
    __shared__ u16 Bs[BN * BK];

    const int tid  = threadIdx.x;
    const int wave = tid >> 6;
    const int lane = tid & 63;

    const int m0 = blockIdx.y * BM;
    const int n0 = blockIdx.x * BN;

    const int wm = (wave >> 1) * 64;   // wave's row block within tile
    const int wn = (wave & 1) * 64;    // wave's col block within tile

    const int fr = lane & 15;          // fragment row (m or n)
    const int fk = (lane >> 4) * 8;    // fragment k offset

    f32x4 acc[4][4] = {};

    // staging: wave w stages rows [w*32, w*32+32) of both tiles, 2 issues of
    // 64 lanes x 16B each. LDS dest = wave-uniform base + lane*16.
    const int srow = wave * 32 + (lane >> 2);
    const int scol = (lane & 3) * 8;
    const u16* ag = A  + (size_t)(m0 + srow) * K + scol;
    const u16* bg = Bt + (size_t)(n0 + srow) * K + scol;
    u16* al0 = As + wave * 1024;
    u16* al1 = As + wave * 1024 + 512;   // rows +16
    u16* bl0 = Bs + wave * 1024;
    u16* bl1 = Bs + wave * 1024 + 512;

    for (int k0 = 0; k0 < K; k0 += BK) {
        gl_lds16(ag + k0,           al0);
        gl_lds16(ag + k0 + 16 * K,  al1);
        gl_lds16(bg + k0,           bl0);
        gl_lds16(bg + k0 + 16 * K,  bl1);
        __syncthreads();

        bf16x8 af[4], bfv[4];
        #pragma unroll
        for (int t = 0; t < 4; ++t) {
            af[t]  = *(const bf16x8*)(As + (wm + t * 16 + fr) * BK + fk);
            bfv[t] = *(const bf16x8*)(Bs + (wn + t * 16 + fr) * BK + fk);
        }
        #pragma unroll
        for (int tm = 0; tm < 4; ++tm)
            #pragma unroll
            for (int tn = 0; tn < 4; ++tn)
                acc[tm][tn] = __builtin_amdgcn_mfma_f32_16x16x32_bf16(
                    af[tm], bfv[tn], acc[tm][tn], 0, 0, 0);
        __syncthreads();
    }

    // epilogue: C/D layout col = lane&15, row = (lane>>4)*4 + reg
    if (IS_QKV) {
        u16* C = (u16*)Cout;
        #pragma unroll
        for (int tm = 0; tm < 4; ++tm) {
            const int r0 = m0 + wm + tm * 16 + (lane >> 4) * 4;
            #pragma unroll
            for (int tn = 0; tn < 4; ++tn) {
                const int col = n0 + wn + tn * 16 + fr;
                const float sc = (col < 768) ? 0.125f : 1.0f;  // q * HD^-0.5
                #pragma unroll
                for (int r = 0; r < 4; ++r)
                    C[(size_t)(r0 + r) * N + col] = f2bf(acc[tm][tn][r] * sc);
            }
        }
    } else {
        float* C = (float*)Cout;
        #pragma unroll
        for (int tm = 0; tm < 4; ++tm) {
            const int r0 = m0 + wm + tm * 16 + (lane >> 4) * 4;
            #pragma unroll
            for (int tn = 0; tn < 4; ++tn) {
                const int col = n0 + wn + tn * 16 + fr;
                const float b = bias[col];
                #pragma unroll
                for (int r = 0; r < 4; ++r)
                    C[(size_t)(r0 + r) * N + col] = acc[tm][tn][r] + b;
            }
        }
    }
}

// ---------------- sparse 3x3-window attention ----------------
// one wave per (b, t, h); lane = head dim. qkv layout [B*N][3*768] bf16,
// q pre-scaled. out [B*N][768] bf16.
__global__ __launch_bounds__(256)
void attn_sparse(const u16* __restrict__ qkv, const float* __restrict__ rpb,
                 u16* __restrict__ out)
{
    const int gw   = blockIdx.x * 4 + (threadIdx.x >> 6);
    const int lane = threadIdx.x & 63;
    const int bt = gw / 12;          // 0..50175
    const int h  = gw - bt * 12;
    const int t  = bt % 196;
    const int i  = t / 14, j = t % 14;

    const float q = bf2f(qkv[(size_t)bt * 2304 + h * 64 + lane]);
    const size_t rowbase = (size_t)(bt - t) * 2304 + h * 64 + lane;

    float s[9], vv[9];
    #pragma unroll
    for (int di = -1; di <= 1; ++di) {
        #pragma unroll
        for (int dj = -1; dj <= 1; ++dj) {
            const int idx = (di + 1) * 3 + (dj + 1);
            const int i2 = i + di, j2 = j + dj;
            const bool valid = ((unsigned)i2 < 14u) && ((unsigned)j2 < 14u);
            const int t2 = valid ? (i2 * 14 + j2) : t;
            const size_t base = rowbase + (size_t)t2 * 2304;
            const float kk = bf2f(qkv[base + 768]);
            vv[idx] = bf2f(qkv[base + 1536]);
            float p = q * kk;
            #pragma unroll
            for (int m = 1; m < 64; m <<= 1) p += __shfl_xor(p, m, 64);
            const int ridx = (13 - di) * 27 + (13 - dj);
            s[idx] = valid ? (p + rpb[ridx * 12 + h]) : -1e30f;
        }
    }
    float mx = s[0];
    #pragma unroll
    for (int a = 1; a < 9; ++a) mx = fmaxf(mx, s[a]);
    float den = 0.f, o = 0.f;
    #pragma unroll
    for (int a = 0; a < 9; ++a) {
        const float p = __expf(s[a] - mx);
        den += p;
        o += p * vv[a];
    }
    out[(size_t)bt * 768 + h * 64 + lane] = f2bf(o / den);
}

// ---------------- launch ----------------
extern "C" void kernel_launch(void* const* d_in, const int* in_sizes, int n_in,
                              void* d_out, int out_size, void* d_ws, size_t ws_size,
                              hipStream_t stream)
{
    const float* x      = (const float*)d_in[0];   // [256,196,768]
    const float* w_qkv  = (const float*)d_in[1];   // [2304,768]
    const float* rpb    = (const float*)d_in[2];   // [729,12]
    const float* proj_w = (const float*)d_in[3];   // [768,768]
    const float* proj_b = (const float*)d_in[4];   // [768]
    // d_in[5] mask, d_in[6] rel_idx: handled analytically
    float* out = (float*)d_out;                    // [256,196,768]

    char* ws = (char*)d_ws;
    u16* x_bf    = (u16*)(ws);                    // 50176*768*2  = 77,070,336 B
    u16* wqkv_bf = (u16*)(ws + 77070336ULL);      // 2304*768*2   =  3,538,944 B
    u16* pw_bf   = (u16*)(ws + 80609280ULL);      // 768*768*2    =  1,179,648 B
    u16* qkv_bf  = (u16*)(ws + 81788928ULL);      // 50176*2304*2 = 231,211,008 B
    u16* attn_bf = (u16*)(ws + 312999936ULL);     // 50176*768*2  = 77,070,336 B
    // total 390,070,272 B

    cvt_bf16<<<37632, 256, 0, stream>>>((const float4*)x,      x_bf,    9633792);
    cvt_bf16<<<1728,  256, 0, stream>>>((const float4*)w_qkv,  wqkv_bf, 442368);
    cvt_bf16<<<576,   256, 0, stream>>>((const float4*)proj_w, pw_bf,   147456);

    // qkv = x @ w_qkv^T  (M=50176, N=2304, K=768), q cols scaled by 0.125
    gemm_bt<true><<<dim3(18, 392), 256, 0, stream>>>(
        x_bf, wqkv_bf, nullptr, qkv_bf, 50176, 2304, 768);

    // sparse local attention: 50176*12 waves
    attn_sparse<<<150528, 256, 0, stream>>>(qkv_bf, rpb, attn_bf);

    // out = attn @ proj_w^T + proj_b  (M=50176, N=768, K=768), fp32 out
    gemm_bt<false><<<dim3(6, 392), 256, 0, stream>>>(
        attn_bf, pw_bf, proj_b, out, 50176, 768, 768);
}

// Round 2
// 757.434 us; speedup vs baseline: 1.5548x; 1.5548x over previous
//
#include <hip/hip_runtime.h>
#include <cstdint>
#include <cstddef>

typedef unsigned short u16;
typedef __attribute__((ext_vector_type(8))) short bf16x8;
typedef __attribute__((ext_vector_type(4))) float f32x4;

__device__ __forceinline__ u16 f2bf(float f) {
    unsigned u = __float_as_uint(f);
    u += 0x7FFF + ((u >> 16) & 1);   // RNE
    return (u16)(u >> 16);
}
__device__ __forceinline__ float bf2f(u16 b) {
    return __uint_as_float(((unsigned)b) << 16);
}

// ---------------- fp32 -> bf16 conversion (4 elems/thread) ----------------
__global__ __launch_bounds__(256) void cvt_bf16(const float4* __restrict__ in,
                                                u16* __restrict__ out, int n4) {
    int i = blockIdx.x * 256 + threadIdx.x;
    if (i >= n4) return;
    float4 v = in[i];
    ushort4 o;
    o.x = f2bf(v.x); o.y = f2bf(v.y); o.z = f2bf(v.z); o.w = f2bf(v.w);
    ((ushort4*)out)[i] = o;
}

// ---------------- bf16 GEMM: C[M,N] = A[M,K] * Bt[N,K]^T ----------------
// 128x128 tile, BK=32, 4 waves (2x2), each wave 4x4 of 16x16x32 MFMA.
constexpr int BM = 128, BN = 128, BK = 32;

__device__ __forceinline__ void gl_lds16(const u16* g, u16* l) {
    __builtin_amdgcn_global_load_lds(
        (const __attribute__((address_space(1))) void*)g,
        (__attribute__((address_space(3))) void*)l, 16, 0, 0);
}

template <bool IS_QKV>
__global__ __launch_bounds__(256)
void gemm_bt(const u16* __restrict__ A, const u16* __restrict__ Bt,
             const float* __restrict__ bias, void* __restrict__ Cout,
             int M, int N, int K)
{
    __shared__ u16 As[BM * BK];
    __shared__ u16 Bs[BN * BK];

    const int tid  = threadIdx.x;
    const int wave = tid >> 6;
    const int lane = tid & 63;

    const int m0 = blockIdx.y * BM;
    const int n0 = blockIdx.x * BN;

    const int wm = (wave >> 1) * 64;   // wave's row block within tile
    const int wn = (wave & 1) * 64;    // wave's col block within tile

    const int fr = lane & 15;          // fragment row (m or n)
    const int fk = (lane >> 4) * 8;    // fragment k offset

    f32x4 acc[4][4] = {};

    // staging: wave w stages rows [w*32, w*32+32) of both tiles, 2 issues of
    // 64 lanes x 16B each. LDS dest = wave-uniform base + lane*16.
    const int srow = wave * 32 + (lane >> 2);
    const int scol = (lane & 3) * 8;
    const u16* ag = A  + (size_t)(m0 + srow) * K + scol;
    const u16* bg = Bt + (size_t)(n0 + srow) * K + scol;
    u16* al0 = As + wave * 1024;
    u16* al1 = As + wave * 1024 + 512;   // rows +16
    u16* bl0 = Bs + wave * 1024;
    u16* bl1 = Bs + wave * 1024 + 512;

    for (int k0 = 0; k0 < K; k0 += BK) {
        gl_lds16(ag + k0,           al0);
        gl_lds16(ag + k0 + 16 * K,  al1);
        gl_lds16(bg + k0,           bl0);
        gl_lds16(bg + k0 + 16 * K,  bl1);
        __syncthreads();

        bf16x8 af[4], bfv[4];
        #pragma unroll
        for (int t = 0; t < 4; ++t) {
            af[t]  = *(const bf16x8*)(As + (wm + t * 16 + fr) * BK + fk);
            bfv[t] = *(const bf16x8*)(Bs + (wn + t * 16 + fr) * BK + fk);
        }
        #pragma unroll
        for (int tm = 0; tm < 4; ++tm)
            #pragma unroll
            for (int tn = 0; tn < 4; ++tn)
                acc[tm][tn] = __builtin_amdgcn_mfma_f32_16x16x32_bf16(
                    af[tm], bfv[tn], acc[tm][tn], 0, 0, 0);
        __syncthreads();
    }

    // epilogue: C/D layout col = lane&15, row = (lane>>4)*4 + reg
    if (IS_QKV) {
        u16* C = (u16*)Cout;
        #pragma unroll
        for (int tm = 0; tm < 4; ++tm) {
            const int r0 = m0 + wm + tm * 16 + (lane >> 4) * 4;
            #pragma unroll
            for (int tn = 0; tn < 4; ++tn) {
                const int col = n0 + wn + tn * 16 + fr;
                const float sc = (col < 768) ? 0.125f : 1.0f;  // q * HD^-0.5
                #pragma unroll
                for (int r = 0; r < 4; ++r)
                    C[(size_t)(r0 + r) * N + col] = f2bf(acc[tm][tn][r] * sc);
            }
        }
    } else {
        float* C = (float*)Cout;
        #pragma unroll
        for (int tm = 0; tm < 4; ++tm) {
            const int r0 = m0 + wm + tm * 16 + (lane >> 4) * 4;
            #pragma unroll
            for (int tn = 0; tn < 4; ++tn) {
                const int col = n0 + wn + tn * 16 + fr;
                const float b = bias[col];
                #pragma unroll
                for (int r = 0; r < 4; ++r)
                    C[(size_t)(r0 + r) * N + col] = acc[tm][tn][r] + b;
            }
        }
    }
}

// ---------------- sparse 3x3-window attention (v2) ----------------
// 8 lanes per query, 8 dims per lane, 8 queries per wave.
// qkv layout [B*N][3*768] bf16, q pre-scaled by 0.125. out [B*N][768] bf16.
__device__ __forceinline__ void load_bf8(const u16* p, float* f) {
    uint4 d = *(const uint4*)p;
    f[0] = __uint_as_float(d.x << 16); f[1] = __uint_as_float(d.x & 0xFFFF0000u);
    f[2] = __uint_as_float(d.y << 16); f[3] = __uint_as_float(d.y & 0xFFFF0000u);
    f[4] = __uint_as_float(d.z << 16); f[5] = __uint_as_float(d.z & 0xFFFF0000u);
    f[6] = __uint_as_float(d.w << 16); f[7] = __uint_as_float(d.w & 0xFFFF0000u);
}

__global__ __launch_bounds__(256)
void attn_sparse2(const u16* __restrict__ qkv, const float* __restrict__ rpb,
                  u16* __restrict__ out)
{
    const int lane = threadIdx.x & 63;
    const int wid  = blockIdx.x * 4 + (threadIdx.x >> 6);
    const int sub  = lane >> 3;          // query within wave (0..7)
    const int sl   = lane & 7;           // dims [sl*8, sl*8+8)
    const int gq   = wid * 8 + sub;      // 0 .. 602111  (= bt*12 + h)
    const int bt   = gq / 12;
    const int h    = gq - bt * 12;
    const int t    = bt % 196;
    const int i    = t / 14, j = t % 14;

    const size_t rowbase = (size_t)(bt - t) * 2304 + h * 64 + sl * 8;

    float qf[8];
    load_bf8(qkv + (size_t)bt * 2304 + h * 64 + sl * 8, qf);

    // pass 1: scores
    float s[9];
    int   t2a[9];
    #pragma unroll
    for (int di = -1; di <= 1; ++di) {
        #pragma unroll
        for (int dj = -1; dj <= 1; ++dj) {
            const int idx = (di + 1) * 3 + (dj + 1);
            const int i2 = i + di, j2 = j + dj;
            const bool valid = ((unsigned)i2 < 14u) && ((unsigned)j2 < 14u);
            const int t2 = valid ? (i2 * 14 + j2) : t;
            t2a[idx] = t2;
            float kf[8];
            load_bf8(qkv + rowbase + (size_t)t2 * 2304 + 768, kf);
            float p = qf[0] * kf[0];
            #pragma unroll
            for (int d = 1; d < 8; ++d) p = fmaf(qf[d], kf[d], p);
            p += __shfl_xor(p, 1);
            p += __shfl_xor(p, 2);
            p += __shfl_xor(p, 4);
            const int ridx = (13 - di) * 27 + (13 - dj);
            s[idx] = valid ? (p + rpb[ridx * 12 + h]) : -1e30f;
        }
    }
    float mx = s[0];
    #pragma unroll
    for (int a = 1; a < 9; ++a) mx = fmaxf(mx, s[a]);

    // pass 2: softmax + weighted V
    float den = 0.f, o[8] = {};
    #pragma unroll
    for (int a = 0; a < 9; ++a) {
        float vf[8];
        load_bf8(qkv + rowbase + (size_t)t2a[a] * 2304 + 1536, vf);
        const float p = __expf(s[a] - mx);   // invalid -> exp(-huge) = 0
        den += p;
        #pragma unroll
        for (int d = 0; d < 8; ++d) o[d] = fmaf(p, vf[d], o[d]);
    }
    const float r = 1.0f / den;
    ushort4 o0, o1;
    o0.x = f2bf(o[0] * r); o0.y = f2bf(o[1] * r);
    o0.z = f2bf(o[2] * r); o0.w = f2bf(o[3] * r);
    o1.x = f2bf(o[4] * r); o1.y = f2bf(o[5] * r);
    o1.z = f2bf(o[6] * r); o1.w = f2bf(o[7] * r);
    u16* op = out + (size_t)bt * 768 + h * 64 + sl * 8;
    *(ushort4*)op = o0;
    *(ushort4*)(op + 4) = o1;
}

// ---------------- launch ----------------
extern "C" void kernel_launch(void* const* d_in, const int* in_sizes, int n_in,
                              void* d_out, int out_size, void* d_ws, size_t ws_size,
                              hipStream_t stream)
{
    const float* x      = (const float*)d_in[0];   // [256,196,768]
    const float* w_qkv  = (const float*)d_in[1];   // [2304,768]
    const float* rpb    = (const float*)d_in[2];   // [729,12]
    const float* proj_w = (const float*)d_in[3];   // [768,768]
    const float* proj_b = (const float*)d_in[4];   // [768]
    // d_in[5] mask, d_in[6] rel_idx: handled analytically
    float* out = (float*)d_out;                    // [256,196,768]

    char* ws = (char*)d_ws;
    u16* x_bf    = (u16*)(ws);                    // 50176*768*2  = 77,070,336 B
    u16* wqkv_bf = (u16*)(ws + 77070336ULL);      // 2304*768*2   =  3,538,944 B
    u16* pw_bf   = (u16*)(ws + 80609280ULL);      // 768*768*2    =  1,179,648 B
    u16* qkv_bf  = (u16*)(ws + 81788928ULL);      // 50176*2304*2 = 231,211,008 B
    u16* attn_bf = (u16*)(ws + 312999936ULL);     // 50176*768*2  = 77,070,336 B
    // total 390,070,272 B

    cvt_bf16<<<37632, 256, 0, stream>>>((const float4*)x,      x_bf,    9633792);
    cvt_bf16<<<1728,  256, 0, stream>>>((const float4*)w_qkv,  wqkv_bf, 442368);
    cvt_bf16<<<576,   256, 0, stream>>>((const float4*)proj_w, pw_bf,   147456);

    // qkv = x @ w_qkv^T  (M=50176, N=2304, K=768), q cols scaled by 0.125
    gemm_bt<true><<<dim3(18, 392), 256, 0, stream>>>(
        x_bf, wqkv_bf, nullptr, qkv_bf, 50176, 2304, 768);

    // sparse local attention: 602112 queries, 8 per wave, 4 waves per block
    attn_sparse2<<<18816, 256, 0, stream>>>(qkv_bf, rpb, attn_bf);

    // out = attn @ proj_w^T + proj_b  (M=50176, N=768, K=768), fp32 out
    gemm_bt<false><<<dim3(6, 392), 256, 0, stream>>>(
        attn_bf, pw_bf, proj_b, out, 50176, 768, 768);
}

// Round 3
// 749.249 us; speedup vs baseline: 1.5718x; 1.0109x over previous
//
#include <hip/hip_runtime.h>
#include <cstdint>
#include <cstddef>

typedef unsigned short u16;
typedef __attribute__((ext_vector_type(8))) short bf16x8;
typedef __attribute__((ext_vector_type(4))) float f32x4;

__device__ __forceinline__ u16 f2bf(float f) {
    unsigned u = __float_as_uint(f);
    u += 0x7FFF + ((u >> 16) & 1);   // RNE
    return (u16)(u >> 16);
}
__device__ __forceinline__ float bf2f(u16 b) {
    return __uint_as_float(((unsigned)b) << 16);
}

// ---------------- fp32 -> bf16 conversion (4 elems/thread) ----------------
__global__ __launch_bounds__(256) void cvt_bf16(const float4* __restrict__ in,
                                                u16* __restrict__ out, int n4) {
    int i = blockIdx.x * 256 + threadIdx.x;
    if (i >= n4) return;
    float4 v = in[i];
    ushort4 o;
    o.x = f2bf(v.x); o.y = f2bf(v.y); o.z = f2bf(v.z); o.w = f2bf(v.w);
    ((ushort4*)out)[i] = o;
}

// ---------------- bf16 GEMM: C[M,N] = A[M,K] * Bt[N,K]^T ----------------
// 128x128 tile, BK=32, 4 waves (2x2), each wave 4x4 of 16x16x32 MFMA.
// LDS layout XOR-swizzled: row r's 16B chunk c lives at chunk c ^ ((r>>1)&3).
// Staging permutes the GLOBAL source chunk per lane (LDS dest of
// global_load_lds is fixed at base + lane*16); reads un-permute. This turns
// the 8-way quarter-wave bank conflict of the naive 64B-row layout into the
// conflict-free streaming pattern (each 8 consecutive rows cover all 32 banks).
constexpr int BM = 128, BN = 128, BK = 32;

__device__ __forceinline__ void gl_lds16(const u16* g, u16* l) {
    __builtin_amdgcn_global_load_lds(
        (const __attribute__((address_space(1))) void*)g,
        (__attribute__((address_space(3))) void*)l, 16, 0, 0);
}

template <bool IS_QKV>
__global__ __launch_bounds__(256)
void gemm_bt(const u16* __restrict__ A, const u16* __restrict__ Bt,
             const float* __restrict__ bias, void* __restrict__ Cout,
             int M, int N, int K)
{
    __shared__ u16 As[BM * BK];
    __shared__ u16 Bs[BN * BK];

    const int tid  = threadIdx.x;
    const int wave = tid >> 6;
    const int lane = tid & 63;

    const int m0 = blockIdx.y * BM;
    const int n0 = blockIdx.x * BN;

    const int wm = (wave >> 1) * 64;   // wave's row block within tile
    const int wn = (wave & 1) * 64;    // wave's col block within tile

    const int fr = lane & 15;          // fragment row (m or n)
    // swizzled k-chunk: logical chunk (lane>>4) xor row-swizzle ((fr>>1)&3)
    const int fks = (((lane >> 4) ^ ((fr >> 1) & 3)) * 8);

    f32x4 acc[4][4] = {};

    // staging: wave w stages rows [w*32, w*32+32) of both tiles, 2 issues of
    // 64 lanes x 16B each. LDS dest = wave-uniform base + lane*16.
    // srow = wave*32 + (lane>>2); swizzle s(srow) = (lane>>3)&3 (stable +16).
    const int srow = wave * 32 + (lane >> 2);
    const int scol = (((lane & 3) ^ ((lane >> 3) & 3)) * 8);
    const u16* ag = A  + (size_t)(m0 + srow) * K + scol;
    const u16* bg = Bt + (size_t)(n0 + srow) * K + scol;
    u16* al0 = As + wave * 1024;
    u16* al1 = As + wave * 1024 + 512;   // rows +16
    u16* bl0 = Bs + wave * 1024;
    u16* bl1 = Bs + wave * 1024 + 512;

    for (int k0 = 0; k0 < K; k0 += BK) {
        gl_lds16(ag + k0,           al0);
        gl_lds16(ag + k0 + 16 * K,  al1);
        gl_lds16(bg + k0,           bl0);
        gl_lds16(bg + k0 + 16 * K,  bl1);
        __syncthreads();

        bf16x8 af[4], bfv[4];
        #pragma unroll
        for (int t = 0; t < 4; ++t) {
            af[t]  = *(const bf16x8*)(As + (wm + t * 16 + fr) * BK + fks);
            bfv[t] = *(const bf16x8*)(Bs + (wn + t * 16 + fr) * BK + fks);
        }
        #pragma unroll
        for (int tm = 0; tm < 4; ++tm)
            #pragma unroll
            for (int tn = 0; tn < 4; ++tn)
                acc[tm][tn] = __builtin_amdgcn_mfma_f32_16x16x32_bf16(
                    af[tm], bfv[tn], acc[tm][tn], 0, 0, 0);
        __syncthreads();
    }

    // epilogue: C/D layout col = lane&15, row = (lane>>4)*4 + reg
    if (IS_QKV) {
        u16* C = (u16*)Cout;
        #pragma unroll
        for (int tm = 0; tm < 4; ++tm) {
            const int r0 = m0 + wm + tm * 16 + (lane >> 4) * 4;
            #pragma unroll
            for (int tn = 0; tn < 4; ++tn) {
                const int col = n0 + wn + tn * 16 + fr;
                const float sc = (col < 768) ? 0.125f : 1.0f;  // q * HD^-0.5
                #pragma unroll
                for (int r = 0; r < 4; ++r)
                    C[(size_t)(r0 + r) * N + col] = f2bf(acc[tm][tn][r] * sc);
            }
        }
    } else {
        float* C = (float*)Cout;
        #pragma unroll
        for (int tm = 0; tm < 4; ++tm) {
            const int r0 = m0 + wm + tm * 16 + (lane >> 4) * 4;
            #pragma unroll
            for (int tn = 0; tn < 4; ++tn) {
                const int col = n0 + wn + tn * 16 + fr;
                const float b = bias[col];
                #pragma unroll
                for (int r = 0; r < 4; ++r)
                    C[(size_t)(r0 + r) * N + col] = acc[tm][tn][r] + b;
            }
        }
    }
}

// ---------------- sparse 3x3-window attention (v2) ----------------
// 8 lanes per query, 8 dims per lane, 8 queries per wave.
// qkv layout [B*N][3*768] bf16, q pre-scaled by 0.125. out [B*N][768] bf16.
__device__ __forceinline__ void load_bf8(const u16* p, float* f) {
    uint4 d = *(const uint4*)p;
    f[0] = __uint_as_float(d.x << 16); f[1] = __uint_as_float(d.x & 0xFFFF0000u);
    f[2] = __uint_as_float(d.y << 16); f[3] = __uint_as_float(d.y & 0xFFFF0000u);
    f[4] = __uint_as_float(d.z << 16); f[5] = __uint_as_float(d.z & 0xFFFF0000u);
    f[6] = __uint_as_float(d.w << 16); f[7] = __uint_as_float(d.w & 0xFFFF0000u);
}

__global__ __launch_bounds__(256)
void attn_sparse2(const u16* __restrict__ qkv, const float* __restrict__ rpb,
                  u16* __restrict__ out)
{
    const int lane = threadIdx.x & 63;
    const int wid  = blockIdx.x * 4 + (threadIdx.x >> 6);
    const int sub  = lane >> 3;          // query within wave (0..7)
    const int sl   = lane & 7;           // dims [sl*8, sl*8+8)
    const int gq   = wid * 8 + sub;      // 0 .. 602111  (= bt*12 + h)
    const int bt   = gq / 12;
    const int h    = gq - bt * 12;
    const int t    = bt % 196;
    const int i    = t / 14, j = t % 14;

    const size_t rowbase = (size_t)(bt - t) * 2304 + h * 64 + sl * 8;

    float qf[8];
    load_bf8(qkv + (size_t)bt * 2304 + h * 64 + sl * 8, qf);

    // pass 1: scores
    float s[9];
    int   t2a[9];
    #pragma unroll
    for (int di = -1; di <= 1; ++di) {
        #pragma unroll
        for (int dj = -1; dj <= 1; ++dj) {
            const int idx = (di + 1) * 3 + (dj + 1);
            const int i2 = i + di, j2 = j + dj;
            const bool valid = ((unsigned)i2 < 14u) && ((unsigned)j2 < 14u);
            const int t2 = valid ? (i2 * 14 + j2) : t;
            t2a[idx] = t2;
            float kf[8];
            load_bf8(qkv + rowbase + (size_t)t2 * 2304 + 768, kf);
            float p = qf[0] * kf[0];
            #pragma unroll
            for (int d = 1; d < 8; ++d) p = fmaf(qf[d], kf[d], p);
            p += __shfl_xor(p, 1);
            p += __shfl_xor(p, 2);
            p += __shfl_xor(p, 4);
            const int ridx = (13 - di) * 27 + (13 - dj);
            s[idx] = valid ? (p + rpb[ridx * 12 + h]) : -1e30f;
        }
    }
    float mx = s[0];
    #pragma unroll
    for (int a = 1; a < 9; ++a) mx = fmaxf(mx, s[a]);

    // pass 2: softmax + weighted V
    float den = 0.f, o[8] = {};
    #pragma unroll
    for (int a = 0; a < 9; ++a) {
        float vf[8];
        load_bf8(qkv + rowbase + (size_t)t2a[a] * 2304 + 1536, vf);
        const float p = __expf(s[a] - mx);   // invalid -> exp(-huge) = 0
        den += p;
        #pragma unroll
        for (int d = 0; d < 8; ++d) o[d] = fmaf(p, vf[d], o[d]);
    }
    const float r = 1.0f / den;
    ushort4 o0, o1;
    o0.x = f2bf(o[0] * r); o0.y = f2bf(o[1] * r);
    o0.z = f2bf(o[2] * r); o0.w = f2bf(o[3] * r);
    o1.x = f2bf(o[4] * r); o1.y = f2bf(o[5] * r);
    o1.z = f2bf(o[6] * r); o1.w = f2bf(o[7] * r);
    u16* op = out + (size_t)bt * 768 + h * 64 + sl * 8;
    *(ushort4*)op = o0;
    *(ushort4*)(op + 4) = o1;
}

// ---------------- launch ----------------
extern "C" void kernel_launch(void* const* d_in, const int* in_sizes, int n_in,
                              void* d_out, int out_size, void* d_ws, size_t ws_size,
                              hipStream_t stream)
{
    const float* x      = (const float*)d_in[0];   // [256,196,768]
    const float* w_qkv  = (const float*)d_in[1];   // [2304,768]
    const float* rpb    = (const float*)d_in[2];   // [729,12]
    const float* proj_w = (const float*)d_in[3];   // [768,768]
    const float* proj_b = (const float*)d_in[4];   // [768]
    // d_in[5] mask, d_in[6] rel_idx: handled analytically
    float* out = (float*)d_out;                    // [256,196,768]

    char* ws = (char*)d_ws;
    u16* x_bf    = (u16*)(ws);                    // 50176*768*2  = 77,070,336 B
    u16* wqkv_bf = (u16*)(ws + 77070336ULL);      // 2304*768*2   =  3,538,944 B
    u16* pw_bf   = (u16*)(ws + 80609280ULL);      // 768*768*2    =  1,179,648 B
    u16* qkv_bf  = (u16*)(ws + 81788928ULL);      // 50176*2304*2 = 231,211,008 B
    u16* attn_bf = (u16*)(ws + 312999936ULL);     // 50176*768*2  = 77,070,336 B
    // total 390,070,272 B

    cvt_bf16<<<37632, 256, 0, stream>>>((const float4*)x,      x_bf,    9633792);
    cvt_bf16<<<1728,  256, 0, stream>>>((const float4*)w_qkv,  wqkv_bf, 442368);
    cvt_bf16<<<576,   256, 0, stream>>>((const float4*)proj_w, pw_bf,   147456);

    // qkv = x @ w_qkv^T  (M=50176, N=2304, K=768), q cols scaled by 0.125
    gemm_bt<true><<<dim3(18, 392), 256, 0, stream>>>(
        x_bf, wqkv_bf, nullptr, qkv_bf, 50176, 2304, 768);

    // sparse local attention: 602112 queries, 8 per wave, 4 waves per block
    attn_sparse2<<<18816, 256, 0, stream>>>(qkv_bf, rpb, attn_bf);

    // out = attn @ proj_w^T + proj_b  (M=50176, N=768, K=768), fp32 out
    gemm_bt<false><<<dim3(6, 392), 256, 0, stream>>>(
        attn_bf, pw_bf, proj_b, out, 50176, 768, 768);
}